// Round 1
// baseline (634.520 us; speedup 1.0000x reference)
//
#include <hip/hip_runtime.h>

typedef int v4i __attribute__((ext_vector_type(4)));

#define MM 8192
#define KK 4096
#define NN 4096
#define NG 8
#define BM 128
#define BN 128
#define BK 64
#define NKT (KK / BK)

// XOR swizzle for an int8 tile stored as 128 rows x 64 bytes.
// Treat row pairs as 128B "lines" of eight 16B slots; slot index is
// XORed with row bits so 16-lane fragment reads (rows r..r+15, fixed
// 16B column) spread 2-way across all 32 banks (free), and staging
// writes stay <=4-way.
__device__ __forceinline__ int swz(int row, int c) {
    int line = row >> 1;
    int s = ((((row & 1) << 2) | (c >> 4)) ^ ((row >> 2) & 7));
    return line * 128 + s * 16 + (c & 15);
}

__global__ __launch_bounds__(256, 2)
void gg_i8(const int* __restrict__ A, const int* __restrict__ B,
           const float* __restrict__ scale, const float* __restrict__ pts,
           const int* __restrict__ glist, float* __restrict__ out)
{
    __shared__ unsigned char Ab[2][BM * BK];
    __shared__ unsigned char Bb[2][BN * BK];

    const int t    = threadIdx.x;
    const int lane = t & 63;
    const int wid  = t >> 6;
    const int wr   = wid >> 1;   // wave row (0..1), 64 rows each
    const int wc   = wid & 1;    // wave col (0..1), 64 cols each

    // XCD-aware swizzle: 2048 blocks % 8 == 0, so the simple form is bijective.
    const int nwg  = gridDim.x;
    const int cpx  = nwg >> 3;
    const int bid  = blockIdx.x;
    const int swzb = (bid & 7) * cpx + (bid >> 3);
    const int mt   = swzb >> 5;          // 64 m-tiles
    const int nt   = swzb & 31;          // 32 n-tiles
    const int brow = mt * BM;
    const int bcol = nt * BN;

    // group of this row-tile (BM=128 divides group size 1024: no straddle)
    int g = 0;
    #pragma unroll
    for (int i = 0; i < NG - 1; ++i)
        if (brow >= glist[i]) g = i + 1;
    const int* Bg = B + g * (KK * NN);

    // ---- staging geometry ----
    // A: thread t loads dwordx4 (4 consecutive k int32) at row (t>>4)+16i,
    //    k-chunk (t&15)*4  -> 16 lanes cover one row's 256B contiguously.
    const int arow = t >> 4;
    const int acol = (t & 15) * 4;          // int32 k index == byte col in tile
    // B: thread t loads dwordx4 (4 consecutive n) at k=(t>>5)*8+j, n=(t&31)*4
    //    -> per-instr 32 lanes cover 512B contiguously; 8 j's give 8 k's for a
    //    register 4x8 transpose, written as 2 dwords (8 k-bytes) per n.
    const int bkq = (t >> 5) * 8;
    const int bnq = (t & 31) * 4;

    const int* aP = A  + (brow + arow) * KK + acol;
    const int* bP = Bg + bkq * NN + bcol + bnq;

    // precomputed swizzled LDS offsets (loop-invariant)
    int awoff[8];
    #pragma unroll
    for (int i = 0; i < 8; ++i) awoff[i] = swz(arow + i * 16, acol);
    int bwoff[4];
    #pragma unroll
    for (int ni = 0; ni < 4; ++ni) bwoff[ni] = swz(bnq + ni, bkq);

    const int fr = lane & 15;
    const int kh = lane >> 4;
    int afoff[4], bfoff[4];
    #pragma unroll
    for (int mi = 0; mi < 4; ++mi) afoff[mi] = swz(wr * 64 + mi * 16 + fr, kh * 16);
    #pragma unroll
    for (int ni = 0; ni < 4; ++ni) bfoff[ni] = swz(wc * 64 + ni * 16 + fr, kh * 16);

    v4i aL[8], bL[8];
    v4i acc[4][4];
    #pragma unroll
    for (int i = 0; i < 4; ++i)
        #pragma unroll
        for (int j = 0; j < 4; ++j)
            acc[i][j] = (v4i){0, 0, 0, 0};

    auto stage_load = [&](int kt) {
        const int* ap = aP + kt * BK;
        #pragma unroll
        for (int i = 0; i < 8; ++i)
            aL[i] = *(const v4i*)(ap + i * 16 * KK);
        const int* bp = bP + kt * BK * NN;
        #pragma unroll
        for (int j = 0; j < 8; ++j)
            bL[j] = *(const v4i*)(bp + j * NN);
    };

    auto stage_write = [&](int buf) {
        #pragma unroll
        for (int i = 0; i < 8; ++i) {
            unsigned pw = (aL[i].x & 255) | ((aL[i].y & 255) << 8) |
                          ((aL[i].z & 255) << 16) | ((unsigned)aL[i].w << 24);
            *(unsigned*)(&Ab[buf][awoff[i]]) = pw;
        }
        #pragma unroll
        for (int ni = 0; ni < 4; ++ni) {
            unsigned lo = (bL[0][ni] & 255) | ((bL[1][ni] & 255) << 8) |
                          ((bL[2][ni] & 255) << 16) | ((unsigned)bL[3][ni] << 24);
            unsigned hi = (bL[4][ni] & 255) | ((bL[5][ni] & 255) << 8) |
                          ((bL[6][ni] & 255) << 16) | ((unsigned)bL[7][ni] << 24);
            unsigned long long w = (unsigned long long)lo |
                                   ((unsigned long long)hi << 32);
            *(unsigned long long*)(&Bb[buf][bwoff[ni]]) = w;
        }
    };

    stage_load(0);
    stage_write(0);
    __syncthreads();

    int cur = 0;
    for (int kt = 0; kt < NKT; ++kt) {
        const bool pf = (kt + 1 < NKT);
        if (pf) stage_load(kt + 1);   // global loads in flight across MFMAs

        v4i af[4], bf[4];
        #pragma unroll
        for (int mi = 0; mi < 4; ++mi)
            af[mi] = *(const v4i*)(&Ab[cur][afoff[mi]]);
        #pragma unroll
        for (int ni = 0; ni < 4; ++ni)
            bf[ni] = *(const v4i*)(&Bb[cur][bfoff[ni]]);

        #pragma unroll
        for (int mi = 0; mi < 4; ++mi)
            #pragma unroll
            for (int ni = 0; ni < 4; ++ni)
                acc[mi][ni] = __builtin_amdgcn_mfma_i32_16x16x64_i8(
                    af[mi], bf[ni], acc[mi][ni], 0, 0, 0);

        if (pf) stage_write(cur ^ 1);
        __syncthreads();
        cur ^= 1;
    }

    // ---- epilogue: dequant + store ----
    #pragma unroll
    for (int mi = 0; mi < 4; ++mi) {
        const int r0 = brow + wr * 64 + mi * 16 + (lane >> 4) * 4;
        #pragma unroll
        for (int ni = 0; ni < 4; ++ni) {
            const int col = bcol + wc * 64 + ni * 16 + (lane & 15);
            const float sc = scale[g * NN + col];
            #pragma unroll
            for (int e = 0; e < 4; ++e) {
                const int r = r0 + e;
                out[r * NN + col] = (float)acc[mi][ni][e] * sc * pts[r];
            }
        }
    }
}

extern "C" void kernel_launch(void* const* d_in, const int* in_sizes, int n_in,
                              void* d_out, int out_size, void* d_ws, size_t ws_size,
                              hipStream_t stream) {
    const int*   A     = (const int*)d_in[0];
    const int*   B     = (const int*)d_in[1];
    const float* scale = (const float*)d_in[2];
    const float* pts   = (const float*)d_in[3];
    const int*   glist = (const int*)d_in[4];
    float*       out   = (float*)d_out;

    dim3 grid((MM / BM) * (NN / BN));
    gg_i8<<<grid, 256, 0, stream>>>(A, B, scale, pts, glist, out);
}

// Round 2
// 420.693 us; speedup vs baseline: 1.5083x; 1.5083x over previous
//
#include <hip/hip_runtime.h>

typedef int v4i __attribute__((ext_vector_type(4)));

#define MM 8192
#define KK 4096
#define NN 4096
#define NG 8
#define BM 128
#define BN 128
#define BK 64
#define NKT (KK / BK)            // 64
#define TILE_BYTES (128 * 64)    // 8 KB per (128-row x 64-k) int8 tile
#define A_TILES_M (MM / BM)      // 64
#define B_TILES_N (NN / BN)      // 32
#define AP_BYTES ((size_t)A_TILES_M * NKT * TILE_BYTES)      // 32 MB
#define BP_BYTES ((size_t)NG * B_TILES_N * NKT * TILE_BYTES) // 128 MB

// XOR swizzle for an int8 tile stored as 128 rows x 64 bytes (16B-slot
// granular). 16-lane fragment reads (16 consecutive rows, fixed 16B col)
// land 2 lanes/bank (free).
__device__ __forceinline__ int swz(int row, int c) {
    int line = row >> 1;
    int s = ((((row & 1) << 2) | (c >> 4)) ^ ((row >> 2) & 7));
    return line * 128 + s * 16 + (c & 15);
}

__device__ __forceinline__ unsigned pack4(v4i v) {
    return (v.x & 255) | ((v.y & 255) << 8) | ((v.z & 255) << 16) |
           ((unsigned)v.w << 24);
}

__device__ __forceinline__ void gload16(const void* g, void* l) {
    __builtin_amdgcn_global_load_lds(
        (const __attribute__((address_space(1))) void*)g,
        (__attribute__((address_space(3))) void*)l, 16, 0, 0);
}

// ---- pack A: int32 [M][K] -> int8 blocked [mt][kt][swz(128x64)] ----
__global__ __launch_bounds__(256)
void pack_a(const int* __restrict__ A, unsigned char* __restrict__ Ap)
{
    const int b  = blockIdx.x;
    const int mt = b >> 6;
    const int kt = b & 63;
    const int t  = threadIdx.x;
    unsigned char* dst = Ap + (size_t)b * TILE_BYTES;

    #pragma unroll
    for (int i = 0; i < 2; ++i) {
        const int p    = t + i * 256;       // 16B output slot index
        const int line = p >> 3, sl = p & 7;
        const int h    = (line >> 1) & 7;
        const int y    = sl ^ h;            // inverse swizzle
        const int row  = 2 * line + (y >> 2);
        const int c16  = y & 3;
        const int* src = A + (size_t)(mt * 128 + row) * KK + kt * 64 + c16 * 16;
        v4i x0 = ((const v4i*)src)[0];
        v4i x1 = ((const v4i*)src)[1];
        v4i x2 = ((const v4i*)src)[2];
        v4i x3 = ((const v4i*)src)[3];
        v4i w;
        w.x = (int)pack4(x0); w.y = (int)pack4(x1);
        w.z = (int)pack4(x2); w.w = (int)pack4(x3);
        *(v4i*)(dst + p * 16) = w;
    }
}

// ---- pack B: int32 [G][K][N] -> int8 blocked [g][nt][kt][swz(128n x 64k)]
// (transpose to K-major while packing) ----
__global__ __launch_bounds__(256)
void pack_b(const int* __restrict__ B, unsigned char* __restrict__ Bp)
{
    const int b  = blockIdx.x;
    const int g  = b >> 11;
    const int nt = (b >> 6) & 31;
    const int kt = b & 63;
    const int t  = threadIdx.x;
    const int k0 = (t >> 5) * 8;
    const int n4 = (t & 31) * 4;

    const int* src = B + (size_t)g * KK * NN + (size_t)(kt * 64 + k0) * NN
                       + nt * 128 + n4;
    v4i r[8];
    #pragma unroll
    for (int j = 0; j < 8; ++j)
        r[j] = *(const v4i*)(src + (size_t)j * NN);

    unsigned char* dst = Bp + (size_t)b * TILE_BYTES;
    #pragma unroll
    for (int n = 0; n < 4; ++n) {
        unsigned lo = (r[0][n] & 255) | ((r[1][n] & 255) << 8) |
                      ((r[2][n] & 255) << 16) | ((unsigned)r[3][n] << 24);
        unsigned hi = (r[4][n] & 255) | ((r[5][n] & 255) << 8) |
                      ((r[6][n] & 255) << 16) | ((unsigned)r[7][n] << 24);
        unsigned long long wv = (unsigned long long)lo |
                                ((unsigned long long)hi << 32);
        *(unsigned long long*)(dst + swz(n4 + n, k0)) = wv;
    }
}

// ---- main GEMM on packed int8 tiles ----
__global__ __launch_bounds__(256)
void gg_i8p(const unsigned char* __restrict__ Ap,
            const unsigned char* __restrict__ Bp,
            const float* __restrict__ scale, const float* __restrict__ pts,
            const int* __restrict__ glist, float* __restrict__ out)
{
    __shared__ unsigned char Ab[2][TILE_BYTES];
    __shared__ unsigned char Bb[2][TILE_BYTES];

    const int t    = threadIdx.x;
    const int lane = t & 63;
    const int wid  = t >> 6;
    const int wr   = wid >> 1;
    const int wc   = wid & 1;

    // XCD-aware swizzle (2048 % 8 == 0 -> bijective)
    const int nwg  = gridDim.x;
    const int cpx  = nwg >> 3;
    const int bid  = blockIdx.x;
    const int swzb = (bid & 7) * cpx + (bid >> 3);
    const int mt   = swzb >> 5;
    const int nt   = swzb & 31;
    const int brow = mt * BM;
    const int bcol = nt * BN;

    int g = 0;
    #pragma unroll
    for (int i = 0; i < NG - 1; ++i)
        if (brow >= glist[i]) g = i + 1;

    const unsigned char* Apblk = Ap + (size_t)mt * NKT * TILE_BYTES;
    const unsigned char* Bpblk = Bp + ((size_t)g * B_TILES_N + nt) * NKT * TILE_BYTES;

    const int wbase = wid * 2048;          // wave-uniform LDS base
    const int goff  = wbase + lane * 16;   // per-lane global offset

    const int fr = lane & 15;
    const int kh = lane >> 4;
    int afoff[4], bfoff[4];
    #pragma unroll
    for (int mi = 0; mi < 4; ++mi) afoff[mi] = swz(wr * 64 + mi * 16 + fr, kh * 16);
    #pragma unroll
    for (int ni = 0; ni < 4; ++ni) bfoff[ni] = swz(wc * 64 + ni * 16 + fr, kh * 16);

    v4i acc[4][4];
    #pragma unroll
    for (int i = 0; i < 4; ++i)
        #pragma unroll
        for (int j = 0; j < 4; ++j)
            acc[i][j] = (v4i){0, 0, 0, 0};

    auto stage = [&](int buf, int kt) {
        const unsigned char* ga = Apblk + (size_t)kt * TILE_BYTES + goff;
        const unsigned char* gb = Bpblk + (size_t)kt * TILE_BYTES + goff;
        #pragma unroll
        for (int c = 0; c < 2; ++c) {
            gload16(ga + c * 1024, &Ab[buf][wbase + c * 1024]);
            gload16(gb + c * 1024, &Bb[buf][wbase + c * 1024]);
        }
    };

    stage(0, 0);
    __syncthreads();

    int cur = 0;
    for (int kt = 0; kt < NKT; ++kt) {
        if (kt + 1 < NKT) stage(cur ^ 1, kt + 1);

        v4i af[4], bf[4];
        #pragma unroll
        for (int mi = 0; mi < 4; ++mi)
            af[mi] = *(const v4i*)(&Ab[cur][afoff[mi]]);
        #pragma unroll
        for (int ni = 0; ni < 4; ++ni)
            bf[ni] = *(const v4i*)(&Bb[cur][bfoff[ni]]);

        #pragma unroll
        for (int mi = 0; mi < 4; ++mi)
            #pragma unroll
            for (int ni = 0; ni < 4; ++ni)
                acc[mi][ni] = __builtin_amdgcn_mfma_i32_16x16x64_i8(
                    af[mi], bf[ni], acc[mi][ni], 0, 0, 0);

        __syncthreads();
        cur ^= 1;
    }

    #pragma unroll
    for (int mi = 0; mi < 4; ++mi) {
        const int r0 = brow + wr * 64 + mi * 16 + (lane >> 4) * 4;
        #pragma unroll
        for (int ni = 0; ni < 4; ++ni) {
            const int col = bcol + wc * 64 + ni * 16 + (lane & 15);
            const float sc = scale[g * NN + col];
            #pragma unroll
            for (int e = 0; e < 4; ++e) {
                const int r = r0 + e;
                out[(size_t)r * NN + col] = (float)acc[mi][ni][e] * sc * pts[r];
            }
        }
    }
}

// ---- round-1 fused fallback (used only if ws_size is too small) ----
__global__ __launch_bounds__(256, 2)
void gg_i8(const int* __restrict__ A, const int* __restrict__ B,
           const float* __restrict__ scale, const float* __restrict__ pts,
           const int* __restrict__ glist, float* __restrict__ out)
{
    __shared__ unsigned char Ab[2][BM * BK];
    __shared__ unsigned char Bb[2][BN * BK];

    const int t    = threadIdx.x;
    const int lane = t & 63;
    const int wid  = t >> 6;
    const int wr   = wid >> 1;
    const int wc   = wid & 1;

    const int nwg  = gridDim.x;
    const int cpx  = nwg >> 3;
    const int bid  = blockIdx.x;
    const int swzb = (bid & 7) * cpx + (bid >> 3);
    const int mt   = swzb >> 5;
    const int nt   = swzb & 31;
    const int brow = mt * BM;
    const int bcol = nt * BN;

    int g = 0;
    #pragma unroll
    for (int i = 0; i < NG - 1; ++i)
        if (brow >= glist[i]) g = i + 1;
    const int* Bg = B + (size_t)g * (KK * NN);

    const int arow = t >> 4;
    const int acol = (t & 15) * 4;
    const int bkq = (t >> 5) * 8;
    const int bnq = (t & 31) * 4;

    const int* aP = A  + (size_t)(brow + arow) * KK + acol;
    const int* bP = Bg + (size_t)bkq * NN + bcol + bnq;

    int awoff[8];
    #pragma unroll
    for (int i = 0; i < 8; ++i) awoff[i] = swz(arow + i * 16, acol);
    int bwoff[4];
    #pragma unroll
    for (int ni = 0; ni < 4; ++ni) bwoff[ni] = swz(bnq + ni, bkq);

    const int fr = lane & 15;
    const int kh = lane >> 4;
    int afoff[4], bfoff[4];
    #pragma unroll
    for (int mi = 0; mi < 4; ++mi) afoff[mi] = swz(wr * 64 + mi * 16 + fr, kh * 16);
    #pragma unroll
    for (int ni = 0; ni < 4; ++ni) bfoff[ni] = swz(wc * 64 + ni * 16 + fr, kh * 16);

    v4i aL[8], bL[8];
    v4i acc[4][4];
    #pragma unroll
    for (int i = 0; i < 4; ++i)
        #pragma unroll
        for (int j = 0; j < 4; ++j)
            acc[i][j] = (v4i){0, 0, 0, 0};

    auto stage_load = [&](int kt) {
        const int* ap = aP + kt * BK;
        #pragma unroll
        for (int i = 0; i < 8; ++i)
            aL[i] = *(const v4i*)(ap + (size_t)i * 16 * KK);
        const int* bp = bP + (size_t)kt * BK * NN;
        #pragma unroll
        for (int j = 0; j < 8; ++j)
            bL[j] = *(const v4i*)(bp + (size_t)j * NN);
    };

    auto stage_write = [&](int buf) {
        #pragma unroll
        for (int i = 0; i < 8; ++i)
            *(unsigned*)(&Ab[buf][awoff[i]]) = pack4(aL[i]);
        #pragma unroll
        for (int ni = 0; ni < 4; ++ni) {
            unsigned lo = (bL[0][ni] & 255) | ((bL[1][ni] & 255) << 8) |
                          ((bL[2][ni] & 255) << 16) | ((unsigned)bL[3][ni] << 24);
            unsigned hi = (bL[4][ni] & 255) | ((bL[5][ni] & 255) << 8) |
                          ((bL[6][ni] & 255) << 16) | ((unsigned)bL[7][ni] << 24);
            unsigned long long w = (unsigned long long)lo |
                                   ((unsigned long long)hi << 32);
            *(unsigned long long*)(&Bb[buf][bwoff[ni]]) = w;
        }
    };

    stage_load(0);
    stage_write(0);
    __syncthreads();

    int cur = 0;
    for (int kt = 0; kt < NKT; ++kt) {
        const bool pf = (kt + 1 < NKT);
        if (pf) stage_load(kt + 1);

        v4i af[4], bf[4];
        #pragma unroll
        for (int mi = 0; mi < 4; ++mi)
            af[mi] = *(const v4i*)(&Ab[cur][afoff[mi]]);
        #pragma unroll
        for (int ni = 0; ni < 4; ++ni)
            bf[ni] = *(const v4i*)(&Bb[cur][bfoff[ni]]);

        #pragma unroll
        for (int mi = 0; mi < 4; ++mi)
            #pragma unroll
            for (int ni = 0; ni < 4; ++ni)
                acc[mi][ni] = __builtin_amdgcn_mfma_i32_16x16x64_i8(
                    af[mi], bf[ni], acc[mi][ni], 0, 0, 0);

        if (pf) stage_write(cur ^ 1);
        __syncthreads();
        cur ^= 1;
    }

    #pragma unroll
    for (int mi = 0; mi < 4; ++mi) {
        const int r0 = brow + wr * 64 + mi * 16 + (lane >> 4) * 4;
        #pragma unroll
        for (int ni = 0; ni < 4; ++ni) {
            const int col = bcol + wc * 64 + ni * 16 + (lane & 15);
            const float sc = scale[g * NN + col];
            #pragma unroll
            for (int e = 0; e < 4; ++e) {
                const int r = r0 + e;
                out[(size_t)r * NN + col] = (float)acc[mi][ni][e] * sc * pts[r];
            }
        }
    }
}

extern "C" void kernel_launch(void* const* d_in, const int* in_sizes, int n_in,
                              void* d_out, int out_size, void* d_ws, size_t ws_size,
                              hipStream_t stream) {
    const int*   A     = (const int*)d_in[0];
    const int*   B     = (const int*)d_in[1];
    const float* scale = (const float*)d_in[2];
    const float* pts   = (const float*)d_in[3];
    const int*   glist = (const int*)d_in[4];
    float*       out   = (float*)d_out;

    if (ws_size >= AP_BYTES + BP_BYTES) {
        unsigned char* Ap = (unsigned char*)d_ws;
        unsigned char* Bp = Ap + AP_BYTES;
        pack_a<<<dim3(A_TILES_M * NKT), 256, 0, stream>>>(A, Ap);
        pack_b<<<dim3(NG * B_TILES_N * NKT), 256, 0, stream>>>(B, Bp);
        gg_i8p<<<dim3((MM / BM) * (NN / BN)), 256, 0, stream>>>(
            Ap, Bp, scale, pts, glist, out);
    } else {
        gg_i8<<<dim3((MM / BM) * (NN / BN)), 256, 0, stream>>>(
            A, B, scale, pts, glist, out);
    }
}

// Round 3
// 321.981 us; speedup vs baseline: 1.9707x; 1.3066x over previous
//
#include <hip/hip_runtime.h>

typedef int v4i __attribute__((ext_vector_type(4)));

#define MM 8192
#define KK 4096
#define NN 4096
#define NG 8
#define TILE_BYTES 8192          // packed tile: 128 rows x 64 k-bytes, swizzled
#define NKT 64                   // K / 64
#define A_TILES_M 64             // M / 128
#define B_TILES_N 32             // N / 128
#define AP_BYTES ((size_t)A_TILES_M * NKT * TILE_BYTES)      // 32 MB
#define BP_BYTES ((size_t)NG * B_TILES_N * NKT * TILE_BYTES) // 128 MB

// GEMM geometry (256^2 tile, 8 waves, 4-deep LDS pipeline)
#define BM 256
#define BN 256
#define NBUF 4
#define ABYTES 16384             // 256 rows x 64 k
#define BBYTES 16384
#define BUFBYTES (ABYTES + BBYTES)   // 32 KB; x4 = 128 KB LDS

// XOR swizzle within a 128-row x 64-byte tile (16B-slot granular).
__device__ __forceinline__ int swz(int row, int c) {
    int line = row >> 1;
    int s = ((((row & 1) << 2) | (c >> 4)) ^ ((row >> 2) & 7));
    return line * 128 + s * 16 + (c & 15);
}

__device__ __forceinline__ unsigned pack4(v4i v) {
    return (v.x & 255) | ((v.y & 255) << 8) | ((v.z & 255) << 16) |
           ((unsigned)v.w << 24);
}

__device__ __forceinline__ void gload16(const void* g, void* l) {
    __builtin_amdgcn_global_load_lds(
        (const __attribute__((address_space(1))) void*)g,
        (__attribute__((address_space(3))) void*)l, 16, 0, 0);
}

// ---- pack A: int32 [M][K] -> int8 blocked [mt][kt][swz(128x64)] ----
__global__ __launch_bounds__(256)
void pack_a(const int* __restrict__ A, unsigned char* __restrict__ Ap)
{
    const int b  = blockIdx.x;
    const int mt = b >> 6;
    const int kt = b & 63;
    const int t  = threadIdx.x;
    unsigned char* dst = Ap + (size_t)b * TILE_BYTES;

    #pragma unroll
    for (int i = 0; i < 2; ++i) {
        const int p    = t + i * 256;       // 16B output slot index
        const int line = p >> 3, sl = p & 7;
        const int h    = (line >> 1) & 7;
        const int y    = sl ^ h;            // inverse swizzle
        const int row  = 2 * line + (y >> 2);
        const int c16  = y & 3;
        const int* src = A + (size_t)(mt * 128 + row) * KK + kt * 64 + c16 * 16;
        v4i x0 = ((const v4i*)src)[0];
        v4i x1 = ((const v4i*)src)[1];
        v4i x2 = ((const v4i*)src)[2];
        v4i x3 = ((const v4i*)src)[3];
        v4i w;
        w.x = (int)pack4(x0); w.y = (int)pack4(x1);
        w.z = (int)pack4(x2); w.w = (int)pack4(x3);
        *(v4i*)(dst + p * 16) = w;
    }
}

// ---- pack B: int32 [G][K][N] -> int8 blocked [g][nt][kt][swz(128n x 64k)] ----
__global__ __launch_bounds__(256)
void pack_b(const int* __restrict__ B, unsigned char* __restrict__ Bp)
{
    const int b  = blockIdx.x;
    const int g  = b >> 11;
    const int nt = (b >> 6) & 31;
    const int kt = b & 63;
    const int t  = threadIdx.x;
    const int k0 = (t >> 5) * 8;
    const int n4 = (t & 31) * 4;

    const int* src = B + (size_t)g * KK * NN + (size_t)(kt * 64 + k0) * NN
                       + nt * 128 + n4;
    v4i r[8];
    #pragma unroll
    for (int j = 0; j < 8; ++j)
        r[j] = *(const v4i*)(src + (size_t)j * NN);

    unsigned char* dst = Bp + (size_t)b * TILE_BYTES;
    #pragma unroll
    for (int n = 0; n < 4; ++n) {
        unsigned lo = (r[0][n] & 255) | ((r[1][n] & 255) << 8) |
                      ((r[2][n] & 255) << 16) | ((unsigned)r[3][n] << 24);
        unsigned hi = (r[4][n] & 255) | ((r[5][n] & 255) << 8) |
                      ((r[6][n] & 255) << 16) | ((unsigned)r[7][n] << 24);
        unsigned long long wv = (unsigned long long)lo |
                                ((unsigned long long)hi << 32);
        *(unsigned long long*)(dst + swz(n4 + n, k0)) = wv;
    }
}

// ---- main GEMM: 256x256 tile, 8 waves, 4-buffer counted-vmcnt pipeline ----
__global__ __launch_bounds__(512, 2)
void gg_i8p2(const unsigned char* __restrict__ Ap,
             const unsigned char* __restrict__ Bp,
             const float* __restrict__ scale, const float* __restrict__ pts,
             const int* __restrict__ glist, float* __restrict__ out)
{
    __shared__ unsigned char lds[NBUF * BUFBYTES];   // 128 KB

    const int t    = threadIdx.x;
    const int lane = t & 63;
    const int wid  = t >> 6;       // 0..7
    const int wr   = wid >> 2;     // 0..1  (M split)
    const int wc   = wid & 3;      // 0..3  (N split)

    // XCD-aware swizzle (512 % 8 == 0 -> bijective)
    const int nwg  = gridDim.x;
    const int cpx  = nwg >> 3;
    const int bid  = blockIdx.x;
    const int swzb = (bid & 7) * cpx + (bid >> 3);
    const int mtc  = swzb >> 4;    // 0..31
    const int ntc  = swzb & 15;    // 0..15
    const int brow = mtc * BM;
    const int bcol = ntc * BN;

    int g = 0;
    #pragma unroll
    for (int i = 0; i < NG - 1; ++i)
        if (brow >= glist[i]) g = i + 1;

    const unsigned char* apg0 = Ap + (size_t)(2 * mtc)     * NKT * TILE_BYTES;
    const unsigned char* apg1 = Ap + (size_t)(2 * mtc + 1) * NKT * TILE_BYTES;
    const unsigned char* bpg0 = Bp + ((size_t)g * B_TILES_N + 2 * ntc)     * NKT * TILE_BYTES;
    const unsigned char* bpg1 = Bp + ((size_t)g * B_TILES_N + 2 * ntc + 1) * NKT * TILE_BYTES;

    const int ldsch = wid * 1024;          // wave-uniform chunk base
    const int gch   = ldsch + lane * 16;   // per-lane global offset

    // fragment LDS offsets (within one buffer)
    const int fr = lane & 15;
    const int kh = lane >> 4;
    int afoff[8], bfoff[4];
    #pragma unroll
    for (int m = 0; m < 8; ++m) {
        const int row = wr * 128 + m * 16 + fr;
        afoff[m] = (row >> 7) * 8192 + swz(row & 127, kh * 16);
    }
    #pragma unroll
    for (int n = 0; n < 4; ++n) {
        const int row = wc * 64 + n * 16 + fr;
        bfoff[n] = ABYTES + (row >> 7) * 8192 + swz(row & 127, kh * 16);
    }

    v4i acc[8][4];
    #pragma unroll
    for (int i = 0; i < 8; ++i)
        #pragma unroll
        for (int j = 0; j < 4; ++j)
            acc[i][j] = (v4i){0, 0, 0, 0};

    // stage one K-tile (4 x gload16 per thread, rises vmcnt by 4)
    auto stage = [&](int buf, int kt) {
        const size_t tk = (size_t)kt * TILE_BYTES;
        unsigned char* la = &lds[buf * BUFBYTES];
        gload16(apg0 + tk + gch, la + ldsch);
        gload16(apg1 + tk + gch, la + 8192 + ldsch);
        gload16(bpg0 + tk + gch, la + ABYTES + ldsch);
        gload16(bpg1 + tk + gch, la + ABYTES + 8192 + ldsch);
    };

    stage(0, 0);
    stage(1, 1);
    stage(2, 2);                   // 12 loads in flight

    #pragma unroll 1
    for (int kt = 0; kt < NKT; ++kt) {
        // drain only the oldest stage; keep the rest in flight (T4)
        if (kt < NKT - 2)       asm volatile("s_waitcnt vmcnt(8)" ::: "memory");
        else if (kt == NKT - 2) asm volatile("s_waitcnt vmcnt(4)" ::: "memory");
        else                    asm volatile("s_waitcnt vmcnt(0)" ::: "memory");
        __builtin_amdgcn_s_barrier();
        asm volatile("" ::: "memory");   // keep frag reads below the barrier

        if (kt + 3 < NKT) stage((kt + 3) & 3, kt + 3);

        const unsigned char* lb = &lds[(kt & 3) * BUFBYTES];
        v4i af[8], bf[4];
        #pragma unroll
        for (int m = 0; m < 8; ++m)
            af[m] = *(const v4i*)(lb + afoff[m]);
        #pragma unroll
        for (int n = 0; n < 4; ++n)
            bf[n] = *(const v4i*)(lb + bfoff[n]);

        __builtin_amdgcn_s_setprio(1);
        #pragma unroll
        for (int m = 0; m < 8; ++m)
            #pragma unroll
            for (int n = 0; n < 4; ++n)
                acc[m][n] = __builtin_amdgcn_mfma_i32_16x16x64_i8(
                    af[m], bf[n], acc[m][n], 0, 0, 0);
        __builtin_amdgcn_s_setprio(0);
    }

    // ---- epilogue: dequant + store ----
    #pragma unroll
    for (int mi = 0; mi < 8; ++mi) {
        const int r0 = brow + wr * 128 + mi * 16 + (lane >> 4) * 4;
        float pt[4];
        #pragma unroll
        for (int e = 0; e < 4; ++e) pt[e] = pts[r0 + e];
        #pragma unroll
        for (int ni = 0; ni < 4; ++ni) {
            const int col = bcol + wc * 64 + ni * 16 + (lane & 15);
            const float sc = scale[g * NN + col];
            #pragma unroll
            for (int e = 0; e < 4; ++e)
                out[(size_t)(r0 + e) * NN + col] = (float)acc[mi][ni][e] * sc * pt[e];
        }
    }
}

// ---- fused fallback (only if ws too small; round-1 verified kernel) ----
__global__ __launch_bounds__(256, 2)
void gg_i8(const int* __restrict__ A, const int* __restrict__ B,
           const float* __restrict__ scale, const float* __restrict__ pts,
           const int* __restrict__ glist, float* __restrict__ out)
{
    __shared__ unsigned char Ab[2][128 * 64];
    __shared__ unsigned char Bb[2][128 * 64];

    const int t    = threadIdx.x;
    const int lane = t & 63;
    const int wid  = t >> 6;
    const int wr   = wid >> 1;
    const int wc   = wid & 1;

    const int nwg  = gridDim.x;
    const int cpx  = nwg >> 3;
    const int bid  = blockIdx.x;
    const int swzb = (bid & 7) * cpx + (bid >> 3);
    const int mt   = swzb >> 5;
    const int nt   = swzb & 31;
    const int brow = mt * 128;
    const int bcol = nt * 128;

    int g = 0;
    #pragma unroll
    for (int i = 0; i < NG - 1; ++i)
        if (brow >= glist[i]) g = i + 1;
    const int* Bg = B + (size_t)g * (KK * NN);

    const int arow = t >> 4;
    const int acol = (t & 15) * 4;
    const int bkq = (t >> 5) * 8;
    const int bnq = (t & 31) * 4;

    const int* aP = A  + (size_t)(brow + arow) * KK + acol;
    const int* bP = Bg + (size_t)bkq * NN + bcol + bnq;

    int awoff[8];
    #pragma unroll
    for (int i = 0; i < 8; ++i) awoff[i] = swz(arow + i * 16, acol);
    int bwoff[4];
    #pragma unroll
    for (int ni = 0; ni < 4; ++ni) bwoff[ni] = swz(bnq + ni, bkq);

    const int fr = lane & 15;
    const int kh = lane >> 4;
    int afoff[4], bfoff[4];
    #pragma unroll
    for (int mi = 0; mi < 4; ++mi) afoff[mi] = swz(wr * 64 + mi * 16 + fr, kh * 16);
    #pragma unroll
    for (int ni = 0; ni < 4; ++ni) bfoff[ni] = swz(wc * 64 + ni * 16 + fr, kh * 16);

    v4i aL[8], bL[8];
    v4i acc[4][4];
    #pragma unroll
    for (int i = 0; i < 4; ++i)
        #pragma unroll
        for (int j = 0; j < 4; ++j)
            acc[i][j] = (v4i){0, 0, 0, 0};

    auto stage_load = [&](int kt) {
        const int* ap = aP + kt * 64;
        #pragma unroll
        for (int i = 0; i < 8; ++i)
            aL[i] = *(const v4i*)(ap + (size_t)i * 16 * KK);
        const int* bp = bP + (size_t)kt * 64 * NN;
        #pragma unroll
        for (int j = 0; j < 8; ++j)
            bL[j] = *(const v4i*)(bp + (size_t)j * NN);
    };

    auto stage_write = [&](int buf) {
        #pragma unroll
        for (int i = 0; i < 8; ++i)
            *(unsigned*)(&Ab[buf][awoff[i]]) = pack4(aL[i]);
        #pragma unroll
        for (int ni = 0; ni < 4; ++ni) {
            unsigned lo = (bL[0][ni] & 255) | ((bL[1][ni] & 255) << 8) |
                          ((bL[2][ni] & 255) << 16) | ((unsigned)bL[3][ni] << 24);
            unsigned hi = (bL[4][ni] & 255) | ((bL[5][ni] & 255) << 8) |
                          ((bL[6][ni] & 255) << 16) | ((unsigned)bL[7][ni] << 24);
            unsigned long long w = (unsigned long long)lo |
                                   ((unsigned long long)hi << 32);
            *(unsigned long long*)(&Bb[buf][bwoff[ni]]) = w;
        }
    };

    stage_load(0);
    stage_write(0);
    __syncthreads();

    int cur = 0;
    for (int kt = 0; kt < NKT; ++kt) {
        const bool pf = (kt + 1 < NKT);
        if (pf) stage_load(kt + 1);

        v4i af[4], bf[4];
        #pragma unroll
        for (int mi = 0; mi < 4; ++mi)
            af[mi] = *(const v4i*)(&Ab[cur][afoff[mi]]);
        #pragma unroll
        for (int ni = 0; ni < 4; ++ni)
            bf[ni] = *(const v4i*)(&Bb[cur][bfoff[ni]]);

        #pragma unroll
        for (int mi = 0; mi < 4; ++mi)
            #pragma unroll
            for (int ni = 0; ni < 4; ++ni)
                acc[mi][ni] = __builtin_amdgcn_mfma_i32_16x16x64_i8(
                    af[mi], bf[ni], acc[mi][ni], 0, 0, 0);

        if (pf) stage_write(cur ^ 1);
        __syncthreads();
        cur ^= 1;
    }

    #pragma unroll
    for (int mi = 0; mi < 4; ++mi) {
        const int r0 = brow + wr * 64 + mi * 16 + (lane >> 4) * 4;
        #pragma unroll
        for (int ni = 0; ni < 4; ++ni) {
            const int col = bcol + wc * 64 + ni * 16 + (lane & 15);
            const float sc = scale[g * NN + col];
            #pragma unroll
            for (int e = 0; e < 4; ++e) {
                const int r = r0 + e;
                out[(size_t)r * NN + col] = (float)acc[mi][ni][e] * sc * pts[r];
            }
        }
    }
}

extern "C" void kernel_launch(void* const* d_in, const int* in_sizes, int n_in,
                              void* d_out, int out_size, void* d_ws, size_t ws_size,
                              hipStream_t stream) {
    const int*   A     = (const int*)d_in[0];
    const int*   B     = (const int*)d_in[1];
    const float* scale = (const float*)d_in[2];
    const float* pts   = (const float*)d_in[3];
    const int*   glist = (const int*)d_in[4];
    float*       out   = (float*)d_out;

    if (ws_size >= AP_BYTES + BP_BYTES) {
        unsigned char* Ap = (unsigned char*)d_ws;
        unsigned char* Bp = Ap + AP_BYTES;
        pack_a<<<dim3(A_TILES_M * NKT), 256, 0, stream>>>(A, Ap);
        pack_b<<<dim3(NG * B_TILES_N * NKT), 256, 0, stream>>>(B, Bp);
        gg_i8p2<<<dim3((MM / BM) * (NN / BN)), 512, 0, stream>>>(
            Ap, Bp, scale, pts, glist, out);
    } else {
        gg_i8<<<dim3((MM / 128) * (NN / 128)), 256, 0, stream>>>(
            A, B, scale, pts, glist, out);
    }
}

// Round 4
// 313.666 us; speedup vs baseline: 2.0229x; 1.0265x over previous
//
#include <hip/hip_runtime.h>

typedef int v4i __attribute__((ext_vector_type(4)));

#define MM 8192
#define KK 4096
#define NN 4096
#define NG 8
#define TILE_BYTES 8192          // packed tile: 128 rows x 64 k-bytes, swizzled
#define NKT 64                   // K / 64
#define NIT (NKT / 2)            // 2 K-tiles per main-loop iteration
#define A_TILES_M 64             // M / 128
#define B_TILES_N 32             // N / 128
#define AP_BYTES ((size_t)A_TILES_M * NKT * TILE_BYTES)      // 32 MB
#define BP_BYTES ((size_t)NG * B_TILES_N * NKT * TILE_BYTES) // 128 MB

// GEMM geometry (256^2 tile, 8 waves, 4-deep LDS pipeline)
#define BM 256
#define BN 256
#define NBUF 4
#define ABYTES 16384             // 256 rows x 64 k
#define BBYTES 16384
#define BUFBYTES (ABYTES + BBYTES)   // 32 KB; x4 = 128 KB LDS

// XOR swizzle within a 128-row x 64-byte tile (16B-slot granular).
__device__ __forceinline__ int swz(int row, int c) {
    int line = row >> 1;
    int s = ((((row & 1) << 2) | (c >> 4)) ^ ((row >> 2) & 7));
    return line * 128 + s * 16 + (c & 15);
}

__device__ __forceinline__ unsigned pack4(v4i v) {
    return (v.x & 255) | ((v.y & 255) << 8) | ((v.z & 255) << 16) |
           ((unsigned)v.w << 24);
}

__device__ __forceinline__ void gload16(const void* g, void* l) {
    __builtin_amdgcn_global_load_lds(
        (const __attribute__((address_space(1))) void*)g,
        (__attribute__((address_space(3))) void*)l, 16, 0, 0);
}

// ---- pack A: int32 [M][K] -> int8 blocked [mt][kt][swz(128x64)] ----
__global__ __launch_bounds__(256)
void pack_a(const int* __restrict__ A, unsigned char* __restrict__ Ap)
{
    const int b  = blockIdx.x;
    const int mt = b >> 6;
    const int kt = b & 63;
    const int t  = threadIdx.x;
    unsigned char* dst = Ap + (size_t)b * TILE_BYTES;

    #pragma unroll
    for (int i = 0; i < 2; ++i) {
        const int p    = t + i * 256;       // 16B output slot index
        const int line = p >> 3, sl = p & 7;
        const int h    = (line >> 1) & 7;
        const int y    = sl ^ h;            // inverse swizzle
        const int row  = 2 * line + (y >> 2);
        const int c16  = y & 3;
        const int* src = A + (size_t)(mt * 128 + row) * KK + kt * 64 + c16 * 16;
        v4i x0 = ((const v4i*)src)[0];
        v4i x1 = ((const v4i*)src)[1];
        v4i x2 = ((const v4i*)src)[2];
        v4i x3 = ((const v4i*)src)[3];
        v4i w;
        w.x = (int)pack4(x0); w.y = (int)pack4(x1);
        w.z = (int)pack4(x2); w.w = (int)pack4(x3);
        *(v4i*)(dst + p * 16) = w;
    }
}

// ---- pack B: int32 [G][K][N] -> int8 blocked [g][nt][kt][swz(128n x 64k)] ----
__global__ __launch_bounds__(256)
void pack_b(const int* __restrict__ B, unsigned char* __restrict__ Bp)
{
    const int b  = blockIdx.x;
    const int g  = b >> 11;
    const int nt = (b >> 6) & 31;
    const int kt = b & 63;
    const int t  = threadIdx.x;
    const int k0 = (t >> 5) * 8;
    const int n4 = (t & 31) * 4;

    const int* src = B + (size_t)g * KK * NN + (size_t)(kt * 64 + k0) * NN
                       + nt * 128 + n4;
    v4i r[8];
    #pragma unroll
    for (int j = 0; j < 8; ++j)
        r[j] = *(const v4i*)(src + (size_t)j * NN);

    unsigned char* dst = Bp + (size_t)b * TILE_BYTES;
    #pragma unroll
    for (int n = 0; n < 4; ++n) {
        unsigned lo = (r[0][n] & 255) | ((r[1][n] & 255) << 8) |
                      ((r[2][n] & 255) << 16) | ((unsigned)r[3][n] << 24);
        unsigned hi = (r[4][n] & 255) | ((r[5][n] & 255) << 8) |
                      ((r[6][n] & 255) << 16) | ((unsigned)r[7][n] << 24);
        unsigned long long wv = (unsigned long long)lo |
                                ((unsigned long long)hi << 32);
        *(unsigned long long*)(dst + swz(n4 + n, k0)) = wv;
    }
}

// ---- main GEMM: 256x256 tile, 8 waves, 4-phase interleave, counted vmcnt ----
__global__ __launch_bounds__(512, 2)
void gg_i8p3(const unsigned char* __restrict__ Ap,
             const unsigned char* __restrict__ Bp,
             const float* __restrict__ scale, const float* __restrict__ pts,
             const int* __restrict__ glist, float* __restrict__ out)
{
    __shared__ unsigned char lds[NBUF * BUFBYTES];   // 128 KB

    const int t    = threadIdx.x;
    const int lane = t & 63;
    const int wid  = t >> 6;       // 0..7
    const int wr   = wid >> 2;     // 0..1  (M split)
    const int wc   = wid & 3;      // 0..3  (N split)

    // XCD-aware swizzle (512 % 8 == 0 -> bijective)
    const int nwg  = gridDim.x;
    const int cpx  = nwg >> 3;
    const int bid  = blockIdx.x;
    const int swzb = (bid & 7) * cpx + (bid >> 3);
    const int mtc  = swzb >> 4;    // 0..31
    const int ntc  = swzb & 15;    // 0..15
    const int brow = mtc * BM;
    const int bcol = ntc * BN;

    int g = 0;
    #pragma unroll
    for (int i = 0; i < NG - 1; ++i)
        if (brow >= glist[i]) g = i + 1;

    const unsigned char* apg0 = Ap + (size_t)(2 * mtc)     * NKT * TILE_BYTES;
    const unsigned char* apg1 = Ap + (size_t)(2 * mtc + 1) * NKT * TILE_BYTES;
    const unsigned char* bpg0 = Bp + ((size_t)g * B_TILES_N + 2 * ntc)     * NKT * TILE_BYTES;
    const unsigned char* bpg1 = Bp + ((size_t)g * B_TILES_N + 2 * ntc + 1) * NKT * TILE_BYTES;

    const int ldsch = wid * 1024;          // wave-uniform chunk base
    const int gch   = ldsch + lane * 16;   // per-lane global offset

    // fragment LDS offsets (within one buffer)
    const int fr = lane & 15;
    const int kh = lane >> 4;
    int afoff[8], bfoff[4];
    #pragma unroll
    for (int m = 0; m < 8; ++m) {
        const int row = wr * 128 + m * 16 + fr;
        afoff[m] = (row >> 7) * 8192 + swz(row & 127, kh * 16);
    }
    #pragma unroll
    for (int n = 0; n < 4; ++n) {
        const int row = wc * 64 + n * 16 + fr;
        bfoff[n] = ABYTES + (row >> 7) * 8192 + swz(row & 127, kh * 16);
    }

    v4i acc[8][4];
    #pragma unroll
    for (int i = 0; i < 8; ++i)
        #pragma unroll
        for (int j = 0; j < 4; ++j)
            acc[i][j] = (v4i){0, 0, 0, 0};

    // one K-tile stage = 4 x gload16 per thread (A0,A1,B0,B1 chunks)
    auto stageA = [&](int kt) {
        const size_t tk = (size_t)kt * TILE_BYTES;
        unsigned char* la = &lds[(kt & 3) * BUFBYTES];
        gload16(apg0 + tk + gch, la + ldsch);
        gload16(apg1 + tk + gch, la + 8192 + ldsch);
    };
    auto stageB = [&](int kt) {
        const size_t tk = (size_t)kt * TILE_BYTES;
        unsigned char* la = &lds[(kt & 3) * BUFBYTES];
        gload16(bpg0 + tk + gch, la + ABYTES + ldsch);
        gload16(bpg1 + tk + gch, la + ABYTES + 8192 + ldsch);
    };

    // prologue: tiles 0,1,2 in flight (12 loads/thread)
    stageA(0); stageB(0);
    stageA(1); stageB(1);
    stageA(2); stageB(2);

    #pragma unroll 1
    for (int it = 0; it < NIT; ++it) {
        const int t0 = 2 * it;
        const unsigned char* lb0 = &lds[(t0 & 3) * BUFBYTES];
        const unsigned char* lb1 = &lds[((t0 + 1) & 3) * BUFBYTES];
        const bool pf01 = (t0 + 3 < NKT);   // stage(t0+3) split over ph0/ph1
        const bool pf23 = (t0 + 4 < NKT);   // stage(t0+4) split over ph2/ph3

        v4i af[4], af2[4], bf[4];

        // ---------- phase 0: tile t0, rows m0-3 ----------
        // steady state: 2 stages (8 loads) may remain behind the needed one
        if (it < NIT - 1) asm volatile("s_waitcnt vmcnt(8)" ::: "memory");
        else              asm volatile("s_waitcnt vmcnt(4)" ::: "memory");
        __builtin_amdgcn_s_barrier();
        asm volatile("" ::: "memory");

        #pragma unroll
        for (int m = 0; m < 4; ++m) af[m] = *(const v4i*)(lb0 + afoff[m]);
        #pragma unroll
        for (int n = 0; n < 4; ++n) bf[n] = *(const v4i*)(lb0 + bfoff[n]);
        if (pf01) stageA(t0 + 3);

        __builtin_amdgcn_s_setprio(1);
        #pragma unroll
        for (int m = 0; m < 4; ++m)
            #pragma unroll
            for (int n = 0; n < 4; ++n)
                acc[m][n] = __builtin_amdgcn_mfma_i32_16x16x64_i8(
                    af[m], bf[n], acc[m][n], 0, 0, 0);
        __builtin_amdgcn_s_setprio(0);

        // ---------- phase 1: tile t0, rows m4-7 ----------
        asm volatile("" ::: "memory");
        __builtin_amdgcn_s_barrier();
        asm volatile("" ::: "memory");

        #pragma unroll
        for (int m = 0; m < 4; ++m) af2[m] = *(const v4i*)(lb0 + afoff[m + 4]);
        if (pf01) stageB(t0 + 3);

        __builtin_amdgcn_s_setprio(1);
        #pragma unroll
        for (int m = 0; m < 4; ++m)
            #pragma unroll
            for (int n = 0; n < 4; ++n)
                acc[m + 4][n] = __builtin_amdgcn_mfma_i32_16x16x64_i8(
                    af2[m], bf[n], acc[m + 4][n], 0, 0, 0);
        __builtin_amdgcn_s_setprio(0);

        // ---------- phase 2: tile t0+1, rows m0-3 ----------
        if (it < NIT - 1) asm volatile("s_waitcnt vmcnt(8)" ::: "memory");
        else              asm volatile("s_waitcnt vmcnt(0)" ::: "memory");
        __builtin_amdgcn_s_barrier();
        asm volatile("" ::: "memory");

        #pragma unroll
        for (int m = 0; m < 4; ++m) af[m] = *(const v4i*)(lb1 + afoff[m]);
        #pragma unroll
        for (int n = 0; n < 4; ++n) bf[n] = *(const v4i*)(lb1 + bfoff[n]);
        if (pf23) stageA(t0 + 4);

        __builtin_amdgcn_s_setprio(1);
        #pragma unroll
        for (int m = 0; m < 4; ++m)
            #pragma unroll
            for (int n = 0; n < 4; ++n)
                acc[m][n] = __builtin_amdgcn_mfma_i32_16x16x64_i8(
                    af[m], bf[n], acc[m][n], 0, 0, 0);
        __builtin_amdgcn_s_setprio(0);

        // ---------- phase 3: tile t0+1, rows m4-7 ----------
        asm volatile("" ::: "memory");
        __builtin_amdgcn_s_barrier();
        asm volatile("" ::: "memory");

        #pragma unroll
        for (int m = 0; m < 4; ++m) af2[m] = *(const v4i*)(lb1 + afoff[m + 4]);
        if (pf23) stageB(t0 + 4);

        __builtin_amdgcn_s_setprio(1);
        #pragma unroll
        for (int m = 0; m < 4; ++m)
            #pragma unroll
            for (int n = 0; n < 4; ++n)
                acc[m + 4][n] = __builtin_amdgcn_mfma_i32_16x16x64_i8(
                    af2[m], bf[n], acc[m + 4][n], 0, 0, 0);
        __builtin_amdgcn_s_setprio(0);
    }

    // ---- epilogue: dequant + store ----
    #pragma unroll
    for (int mi = 0; mi < 8; ++mi) {
        const int r0 = brow + wr * 128 + mi * 16 + (lane >> 4) * 4;
        float pt[4];
        #pragma unroll
        for (int e = 0; e < 4; ++e) pt[e] = pts[r0 + e];
        #pragma unroll
        for (int ni = 0; ni < 4; ++ni) {
            const int col = bcol + wc * 64 + ni * 16 + (lane & 15);
            const float sc = scale[g * NN + col];
            #pragma unroll
            for (int e = 0; e < 4; ++e)
                out[(size_t)(r0 + e) * NN + col] = (float)acc[mi][ni][e] * sc * pt[e];
        }
    }
}

// ---- fused fallback (only if ws too small; round-1 verified kernel) ----
__global__ __launch_bounds__(256, 2)
void gg_i8(const int* __restrict__ A, const int* __restrict__ B,
           const float* __restrict__ scale, const float* __restrict__ pts,
           const int* __restrict__ glist, float* __restrict__ out)
{
    __shared__ unsigned char Ab[2][128 * 64];
    __shared__ unsigned char Bb[2][128 * 64];

    const int t    = threadIdx.x;
    const int lane = t & 63;
    const int wid  = t >> 6;
    const int wr   = wid >> 1;
    const int wc   = wid & 1;

    const int nwg  = gridDim.x;
    const int cpx  = nwg >> 3;
    const int bid  = blockIdx.x;
    const int swzb = (bid & 7) * cpx + (bid >> 3);
    const int mt   = swzb >> 5;
    const int nt   = swzb & 31;
    const int brow = mt * 128;
    const int bcol = nt * 128;

    int g = 0;
    #pragma unroll
    for (int i = 0; i < NG - 1; ++i)
        if (brow >= glist[i]) g = i + 1;
    const int* Bg = B + (size_t)g * (KK * NN);

    const int arow = t >> 4;
    const int acol = (t & 15) * 4;
    const int bkq = (t >> 5) * 8;
    const int bnq = (t & 31) * 4;

    const int* aP = A  + (size_t)(brow + arow) * KK + acol;
    const int* bP = Bg + (size_t)bkq * NN + bcol + bnq;

    int awoff[8];
    #pragma unroll
    for (int i = 0; i < 8; ++i) awoff[i] = swz(arow + i * 16, acol);
    int bwoff[4];
    #pragma unroll
    for (int ni = 0; ni < 4; ++ni) bwoff[ni] = swz(bnq + ni, bkq);

    const int fr = lane & 15;
    const int kh = lane >> 4;
    int afoff[4], bfoff[4];
    #pragma unroll
    for (int mi = 0; mi < 4; ++mi) afoff[mi] = swz(wr * 64 + mi * 16 + fr, kh * 16);
    #pragma unroll
    for (int ni = 0; ni < 4; ++ni) bfoff[ni] = swz(wc * 64 + ni * 16 + fr, kh * 16);

    v4i aL[8], bL[8];
    v4i acc[4][4];
    #pragma unroll
    for (int i = 0; i < 4; ++i)
        #pragma unroll
        for (int j = 0; j < 4; ++j)
            acc[i][j] = (v4i){0, 0, 0, 0};

    auto stage_load = [&](int kt) {
        const int* ap = aP + kt * 64;
        #pragma unroll
        for (int i = 0; i < 8; ++i)
            aL[i] = *(const v4i*)(ap + (size_t)i * 16 * KK);
        const int* bp = bP + (size_t)kt * 64 * NN;
        #pragma unroll
        for (int j = 0; j < 8; ++j)
            bL[j] = *(const v4i*)(bp + (size_t)j * NN);
    };

    auto stage_write = [&](int buf) {
        #pragma unroll
        for (int i = 0; i < 8; ++i)
            *(unsigned*)(&Ab[buf][awoff[i]]) = pack4(aL[i]);
        #pragma unroll
        for (int ni = 0; ni < 4; ++ni) {
            unsigned lo = (bL[0][ni] & 255) | ((bL[1][ni] & 255) << 8) |
                          ((bL[2][ni] & 255) << 16) | ((unsigned)bL[3][ni] << 24);
            unsigned hi = (bL[4][ni] & 255) | ((bL[5][ni] & 255) << 8) |
                          ((bL[6][ni] & 255) << 16) | ((unsigned)bL[7][ni] << 24);
            unsigned long long w = (unsigned long long)lo |
                                   ((unsigned long long)hi << 32);
            *(unsigned long long*)(&Bb[buf][bwoff[ni]]) = w;
        }
    };

    stage_load(0);
    stage_write(0);
    __syncthreads();

    int cur = 0;
    for (int kt = 0; kt < NKT; ++kt) {
        const bool pf = (kt + 1 < NKT);
        if (pf) stage_load(kt + 1);

        v4i af[4], bf[4];
        #pragma unroll
        for (int mi = 0; mi < 4; ++mi)
            af[mi] = *(const v4i*)(&Ab[cur][afoff[mi]]);
        #pragma unroll
        for (int ni = 0; ni < 4; ++ni)
            bf[ni] = *(const v4i*)(&Bb[cur][bfoff[ni]]);

        #pragma unroll
        for (int mi = 0; mi < 4; ++mi)
            #pragma unroll
            for (int ni = 0; ni < 4; ++ni)
                acc[mi][ni] = __builtin_amdgcn_mfma_i32_16x16x64_i8(
                    af[mi], bf[ni], acc[mi][ni], 0, 0, 0);

        if (pf) stage_write(cur ^ 1);
        __syncthreads();
        cur ^= 1;
    }

    #pragma unroll
    for (int mi = 0; mi < 4; ++mi) {
        const int r0 = brow + wr * 64 + mi * 16 + (lane >> 4) * 4;
        #pragma unroll
        for (int ni = 0; ni < 4; ++ni) {
            const int col = bcol + wc * 64 + ni * 16 + (lane & 15);
            const float sc = scale[g * NN + col];
            #pragma unroll
            for (int e = 0; e < 4; ++e) {
                const int r = r0 + e;
                out[(size_t)r * NN + col] = (float)acc[mi][ni][e] * sc * pts[r];
            }
        }
    }
}

extern "C" void kernel_launch(void* const* d_in, const int* in_sizes, int n_in,
                              void* d_out, int out_size, void* d_ws, size_t ws_size,
                              hipStream_t stream) {
    const int*   A     = (const int*)d_in[0];
    const int*   B     = (const int*)d_in[1];
    const float* scale = (const float*)d_in[2];
    const float* pts   = (const float*)d_in[3];
    const int*   glist = (const int*)d_in[4];
    float*       out   = (float*)d_out;

    if (ws_size >= AP_BYTES + BP_BYTES) {
        unsigned char* Ap = (unsigned char*)d_ws;
        unsigned char* Bp = Ap + AP_BYTES;
        pack_a<<<dim3(A_TILES_M * NKT), 256, 0, stream>>>(A, Ap);
        pack_b<<<dim3(NG * B_TILES_N * NKT), 256, 0, stream>>>(B, Bp);
        gg_i8p3<<<dim3((MM / BM) * (NN / BN)), 512, 0, stream>>>(
            Ap, Bp, scale, pts, glist, out);
    } else {
        gg_i8<<<dim3((MM / 128) * (NN / 128)), 256, 0, stream>>>(
            A, B, scale, pts, glist, out);
    }
}